// Round 6
// baseline (21046.873 us; speedup 1.0000x reference)
//
#include <hip/hip_runtime.h>
#include <math.h>

#define NN    2048      // nodes == hidden
#define TT    64        // horizon
#define KIN   32768     // N_IN * N_NODES
#define KSTAT 30720     // static (non-recurrent) part of W_in columns
#define KPART 8         // K-split for k_pre
#define KC    (KSTAT / KPART)   // 3840
#define RBLK  256       // persistent-kernel blocks (1/CU, 2048 waves)
#define RTPB  512

typedef _Float16 half8v __attribute__((ext_vector_type(8)));
typedef unsigned int uint32;

__device__ __forceinline__ float wred(float v){
  #pragma unroll
  for (int m = 32; m > 0; m >>= 1) v += __shfl_xor(v, m, 64);
  return v;
}
__device__ __forceinline__ float sigm(float x){ return 1.0f / (1.0f + expf(-x)); }

__device__ __forceinline__ void load8(const _Float16* __restrict__ p, float* o){
  half8v h = *(const half8v*)p;
  #pragma unroll
  for (int i = 0; i < 8; ++i) o[i] = (float)h[i];
}
__device__ __forceinline__ void load8(const float* __restrict__ p, float* o){
  float4 a = *(const float4*)p, b = *(const float4*)(p + 4);
  o[0]=a.x; o[1]=a.y; o[2]=a.z; o[3]=a.w; o[4]=b.x; o[5]=b.y; o[6]=b.z; o[7]=b.w;
}

// ---------- lightweight grid barrier (generation counter) ----------
__device__ __forceinline__ void gbar(uint32* cnt, uint32* gen, uint32 nblk){
  __syncthreads();
  if (threadIdx.x == 0){
    __builtin_amdgcn_fence(__ATOMIC_RELEASE, "agent");
    uint32 g0 = __hip_atomic_load(gen, __ATOMIC_RELAXED, __HIP_MEMORY_SCOPE_AGENT);
    uint32 prev = __hip_atomic_fetch_add(cnt, 1u, __ATOMIC_ACQ_REL, __HIP_MEMORY_SCOPE_AGENT);
    if (prev == nblk - 1u){
      __hip_atomic_store(cnt, 0u, __ATOMIC_RELAXED, __HIP_MEMORY_SCOPE_AGENT);
      __hip_atomic_store(gen, g0 + 1u, __ATOMIC_RELEASE, __HIP_MEMORY_SCOPE_AGENT);
    } else {
      while (__hip_atomic_load(gen, __ATOMIC_RELAXED, __HIP_MEMORY_SCOPE_AGENT) == g0)
        __builtin_amdgcn_s_sleep(1);
    }
    __builtin_amdgcn_fence(__ATOMIC_ACQUIRE, "agent");
  }
  __syncthreads();
}

// ---------- f32 -> fp16 conversions ----------
__global__ void k_cvt(const float* __restrict__ s, _Float16* __restrict__ d){
  size_t i = ((size_t)blockIdx.x * 256 + threadIdx.x) * 8;
  float v[8]; load8(s + i, v);
  half8v h;
  #pragma unroll
  for (int q = 0; q < 8; ++q) h[q] = (_Float16)v[q];
  *(half8v*)(d + i) = h;
}
__global__ void k_cvt_tail(const float* __restrict__ Win, _Float16* __restrict__ dst){
  int r = blockIdx.x, c = threadIdx.x * 8;
  float v[8]; load8(Win + (size_t)r * KIN + KSTAT + c, v);
  half8v h;
  #pragma unroll
  for (int q = 0; q < 8; ++q) h[q] = (_Float16)v[q];
  *(half8v*)(dst + (size_t)r * NN + c) = h;
}

// ---------- f32 -> packed 12-bit (1-5-6 truncated fp16) ----------
__global__ void k_pack(const float* __restrict__ W, uint4* __restrict__ P){
  const int row  = blockIdx.x * 4 + (threadIdx.x >> 6);
  const int lane = threadIdx.x & 63;
  const float4* W4 = (const float4*)(W + (size_t)row * NN);
  uint32 u[12] = {0,0,0,0,0,0,0,0,0,0,0,0};
  #pragma unroll
  for (int c = 0; c < 8; ++c){
    float4 v = W4[lane + (c << 6)];
    float vv[4] = {v.x, v.y, v.z, v.w};
    #pragma unroll
    for (int q = 0; q < 4; ++q){
      _Float16 h = (_Float16)vv[q];
      unsigned short us = __builtin_bit_cast(unsigned short, h);
      us = (unsigned short)((us + 8) & 0xFFF0);
      uint32 f = (uint32)(us >> 4);
      int k = 4 * c + q, bp = 12 * k, w = bp >> 5, off = bp & 31;
      u[w] |= f << off;
      if (off > 20) u[w + 1] |= f >> (32 - off);
    }
  }
  uint4* p = P + (size_t)row * 192 + lane;
  p[0]   = make_uint4(u[0], u[1], u[2],  u[3]);
  p[64]  = make_uint4(u[4], u[5], u[6],  u[7]);
  p[128] = make_uint4(u[8], u[9], u[10], u[11]);
}

// ---------- packed-weight dot: one wave, one row of 2048 ----------
__device__ __forceinline__ float dot_packed(const uint4* __restrict__ base, int row,
                                            const float4* __restrict__ v4, int lane){
  const uint4* p = base + (size_t)row * 192 + lane;
  uint4 A = p[0], B = p[64], C = p[128];
  uint32 u[12] = {A.x,A.y,A.z,A.w, B.x,B.y,B.z,B.w, C.x,C.y,C.z,C.w};
  float acc = 0.f;
  #pragma unroll
  for (int c = 0; c < 8; ++c){
    float4 v = v4[lane + (c << 6)];
    float vv[4] = {v.x, v.y, v.z, v.w};
    #pragma unroll
    for (int q = 0; q < 4; ++q){
      int k = 4 * c + q, bp = 12 * k, w = bp >> 5, off = bp & 31;
      uint32 f = u[w] >> off;
      if (off > 20) f |= u[w + 1] << (32 - off);
      f &= 0xFFFu;
      float wt = (float)__builtin_bit_cast(_Float16, (unsigned short)(f << 4));
      acc = fmaf(wt, vv[q], acc);
    }
  }
  return acc;
}

// ---------- LSTM unit: all 4 gates in one wave (cell update wave-local) ----------
__device__ __forceinline__ void lstm_unit(const uint4* __restrict__ Pih, const uint4* __restrict__ Phh,
    const float* __restrict__ bih_l, const float* __restrict__ bhh_l,
    const float* __restrict__ vin, const float* __restrict__ hprev,
    float* __restrict__ c, float* __restrict__ hout, int j, int lane)
{
  float g[4];
  #pragma unroll
  for (int gg = 0; gg < 4; ++gg){
    float a = dot_packed(Pih, gg * NN + j, (const float4*)vin,  lane)
            + dot_packed(Phh, gg * NN + j, (const float4*)hprev, lane);
    g[gg] = wred(a);
  }
  if (lane == 0){
    float gi = sigm(g[0] + bih_l[0 * NN + j] + bhh_l[0 * NN + j]);
    float gf = sigm(g[1] + bih_l[1 * NN + j] + bhh_l[1 * NN + j]);
    float gt = tanhf(g[2] + bih_l[2 * NN + j] + bhh_l[2 * NN + j]);
    float go = sigm(g[3] + bih_l[3 * NN + j] + bhh_l[3 * NN + j]);
    float cn = fmaf(gf, c[j], gi * gt);
    c[j] = cn;
    hout[j] = go * tanhf(cn);
  }
}

// ---------- persistent recurrent kernel: 2048 waves, custom barriers ----------
__global__ __launch_bounds__(RTPB, 4) void k_run(
  const uint4* __restrict__ PIH, const uint4* __restrict__ PHH,
  const _Float16* __restrict__ Wt16, const _Float16* __restrict__ Wo16,
  const float* __restrict__ bih, const float* __restrict__ bhh,
  const float* __restrict__ bout, const float* __restrict__ U,
  float* __restrict__ lin, float* __restrict__ h0b, float* __restrict__ h1b,
  float* __restrict__ c0, float* __restrict__ c1,
  float* __restrict__ xs, float* __restrict__ out,
  uint32* __restrict__ cnt, uint32* __restrict__ gen)
{
  const int w    = (int)blockIdx.x * (RTPB / 64) + ((int)threadIdx.x >> 6);  // 0..2047
  const int lane = (int)threadIdx.x & 63;
  const uint32 nblk = gridDim.x;
  const size_t LROWS = (size_t)4 * NN * 192;

  for (int t = 0; t < TT; ++t){
    const int p = t & 1;
    const float* h0p = h0b + p * NN;  float* h0n = h0b + (1 - p) * NN;
    const float* h1p = h1b + p * NN;  float* h1n = h1b + (1 - p) * NN;

    // stage A: lin[w] = U[w][t] + Wt16[w,:] @ xs
    {
      const _Float16* wp = Wt16 + (size_t)w * NN + lane * 8;
      const float* xv = xs + lane * 8;
      float acc = 0.f;
      #pragma unroll
      for (int ch = 0; ch < 4; ++ch){
        float wf[8], vf[8];
        load8(wp + ch * 512, wf); load8(xv + ch * 512, vf);
        #pragma unroll
        for (int q = 0; q < 8; ++q) acc = fmaf(wf[q], vf[q], acc);
      }
      acc = wred(acc);
      if (lane == 0) lin[w] = U[(size_t)w * TT + t] + acc;
    }
    gbar(cnt, gen, nblk);

    // stage B: layer 0, unit w
    lstm_unit(PIH, PHH, bih, bhh, lin, h0p, c0, h0n, w, lane);
    gbar(cnt, gen, nblk);

    // stage C: layer 1, unit w
    lstm_unit(PIH + LROWS, PHH + LROWS, bih + 4 * NN, bhh + 4 * NN,
              h0n, h1p, c1, h1n, w, lane);
    gbar(cnt, gen, nblk);

    // stage D: xs[w] += tanh(Wo16[w,:] @ h1n + bout[w])
    {
      const _Float16* wp = Wo16 + (size_t)w * NN + lane * 8;
      const float* hv = h1n + lane * 8;
      float acc = 0.f;
      #pragma unroll
      for (int ch = 0; ch < 4; ++ch){
        float wf[8], vf[8];
        load8(wp + ch * 512, wf); load8(hv + ch * 512, vf);
        #pragma unroll
        for (int q = 0; q < 8; ++q) acc = fmaf(wf[q], vf[q], acc);
      }
      acc = wred(acc);
      if (lane == 0){
        float xn = xs[w] + tanhf(acc + bout[w]);
        xs[w] = xn;
        out[(size_t)w * (TT + 1) + t + 1] = xn;
      }
    }
    gbar(cnt, gen, nblk);
  }
}

// ---------- gather static input matrix S[k][t] ----------
__global__ void k_gather(const float* __restrict__ coords, const float* __restrict__ env,
                         const float* __restrict__ dusk, const float* __restrict__ dawn,
                         float* __restrict__ S)
{
  int idx = blockIdx.x * 256 + threadIdx.x;
  int k = idx >> 6, t = idx & 63;
  float v;
  if (k < 4096)        v = coords[k];
  else if (k < 26624)  v = env[(size_t)(k - 4096) * 65 + t + 1];
  else if (k < 28672)  v = dusk[(size_t)(k - 26624) * 64 + t];
  else                 v = dawn[(size_t)(k - 28672) * 65 + t + 1];
  S[idx] = v;
}

// ---------- tiled GEMM: P[part][r][t] = sum_{k in part} W_in[r][k] * S[k][t] ----------
__global__ void k_pre(const float* __restrict__ Win, const float* __restrict__ S,
                      float* __restrict__ P)
{
  __shared__ float Wt[16 * 68];
  __shared__ float St[64 * 68];
  const int tid = threadIdx.x;
  const int rb  = blockIdx.x * 16;
  const int kp  = blockIdx.y;
  const int rc  = tid >> 4;
  const int t4  = (tid & 15) * 4;
  float4 acc = make_float4(0.f, 0.f, 0.f, 0.f);

  for (int kt = 0; kt < KC; kt += 64){
    const int kb = kp * KC + kt;
    __syncthreads();
    *(float4*)(Wt + rc * 68 + t4) =
        *(const float4*)(Win + (size_t)(rb + rc) * KIN + kb + t4);
    #pragma unroll
    for (int jj = 0; jj < 4; ++jj){
      int li = jj * 1024 + tid * 4;
      int kr = li >> 6, tc = li & 63;
      *(float4*)(St + kr * 68 + tc) =
          *(const float4*)(S + (size_t)(kb + kr) * 64 + tc);
    }
    __syncthreads();
    #pragma unroll
    for (int k = 0; k < 64; ++k){
      float w = Wt[rc * 68 + k];
      float4 s = *(const float4*)(St + k * 68 + t4);
      acc.x = fmaf(w, s.x, acc.x);
      acc.y = fmaf(w, s.y, acc.y);
      acc.z = fmaf(w, s.z, acc.z);
      acc.w = fmaf(w, s.w, acc.w);
    }
  }
  *(float4*)(P + ((size_t)kp * NN + rb + rc) * TT + t4) = acc;
}

// ---------- U[r][t] = b_in[r] + sum_p P[p][r][t] ----------
__global__ void k_reduce(const float* __restrict__ P, const float* __restrict__ bin,
                         float* __restrict__ U)
{
  int i = blockIdx.x * 256 + threadIdx.x;
  float s = bin[i >> 6];
  #pragma unroll
  for (int p = 0; p < KPART; ++p) s += P[(size_t)p * NN * TT + i];
  U[i] = s;
}

// ---------- init states + sync words + output column 0 ----------
__global__ void k_init(const float* __restrict__ x, float* __restrict__ xs,
                       float* __restrict__ h0b, float* __restrict__ h1b,
                       float* __restrict__ c0, float* __restrict__ c1,
                       float* __restrict__ out, uint32* __restrict__ sync)
{
  int i = blockIdx.x * blockDim.x + threadIdx.x;
  if (i < 64) sync[i] = 0u;
  if (i < NN){
    float x0 = x[(size_t)i * (TT + 1)];
    xs[i] = x0;
    out[(size_t)i * (TT + 1)] = x0;
    h0b[i] = 0.f; h0b[NN + i] = 0.f;
    h1b[i] = 0.f; h1b[NN + i] = 0.f;
    c0[i] = 0.f;  c1[i] = 0.f;
  }
}

// ---------- f32 fallback kernels (used only if ws too small) ----------
template<typename WT>
__global__ void k_lin_t(const WT* __restrict__ Wtail, size_t wstride,
                        const float* __restrict__ U, const float* __restrict__ xs,
                        float* __restrict__ lin, int t)
{
  const int j    = blockIdx.x * 4 + (threadIdx.x >> 6);
  const int lane = threadIdx.x & 63;
  const WT* w = Wtail + (size_t)j * wstride + lane * 8;
  const float* xv = xs + lane * 8;
  float acc = 0.f;
  #pragma unroll
  for (int ch = 0; ch < 4; ++ch){
    float wf[8], vf[8];
    load8(w + ch * 512, wf);
    load8(xv + ch * 512, vf);
    #pragma unroll
    for (int q = 0; q < 8; ++q) acc = fmaf(wf[q], vf[q], acc);
  }
  acc = wred(acc);
  if (lane == 0) lin[j] = U[(size_t)j * TT + t] + acc;
}

template<typename WT>
__global__ void k_lstm_t(const WT* __restrict__ Wih_l, const WT* __restrict__ Whh_l,
                         const float* __restrict__ bih_l, const float* __restrict__ bhh_l,
                         const float* __restrict__ vin, const float* __restrict__ hprev,
                         float* __restrict__ c, float* __restrict__ hout)
{
  __shared__ float gsm[4];
  const int j    = blockIdx.x;
  const int g    = threadIdx.x >> 6;
  const int lane = threadIdx.x & 63;
  const WT* wi = Wih_l + (size_t)(g * NN + j) * NN + lane * 8;
  const WT* wh = Whh_l + (size_t)(g * NN + j) * NN + lane * 8;
  const float* vi = vin + lane * 8;
  const float* hp = hprev + lane * 8;
  float acc = 0.f;
  #pragma unroll
  for (int ch = 0; ch < 4; ++ch){
    float w1[8], w2[8], v1[8], v2[8];
    load8(wi + ch * 512, w1); load8(vi + ch * 512, v1);
    load8(wh + ch * 512, w2); load8(hp + ch * 512, v2);
    #pragma unroll
    for (int q = 0; q < 8; ++q) acc = fmaf(w1[q], v1[q], fmaf(w2[q], v2[q], acc));
  }
  acc = wred(acc);
  if (lane == 0) gsm[g] = acc + bih_l[g * NN + j] + bhh_l[g * NN + j];
  __syncthreads();
  if (threadIdx.x == 0){
    float gi = sigm(gsm[0]);
    float gf = sigm(gsm[1]);
    float gg = tanhf(gsm[2]);
    float go = sigm(gsm[3]);
    float cn = fmaf(gf, c[j], gi * gg);
    c[j] = cn;
    hout[j] = go * tanhf(cn);
  }
}

template<typename WT>
__global__ void k_xout_t(const WT* __restrict__ Wout, const float* __restrict__ bout,
                         const float* __restrict__ h1, float* __restrict__ xs,
                         float* __restrict__ out, int t)
{
  const int j    = blockIdx.x * 4 + (threadIdx.x >> 6);
  const int lane = threadIdx.x & 63;
  const WT* w = Wout + (size_t)j * NN + lane * 8;
  const float* hv = h1 + lane * 8;
  float acc = 0.f;
  #pragma unroll
  for (int ch = 0; ch < 4; ++ch){
    float wf[8], vf[8];
    load8(w + ch * 512, wf);
    load8(hv + ch * 512, vf);
    #pragma unroll
    for (int q = 0; q < 8; ++q) acc = fmaf(wf[q], vf[q], acc);
  }
  acc = wred(acc);
  if (lane == 0){
    float xn = xs[j] + tanhf(acc + bout[j]);
    xs[j] = xn;
    out[(size_t)j * (TT + 1) + t + 1] = xn;
  }
}

extern "C" void kernel_launch(void* const* d_in, const int* in_sizes, int n_in,
                              void* d_out, int out_size, void* d_ws, size_t ws_size,
                              hipStream_t stream)
{
  const float* x      = (const float*)d_in[0];
  const float* coords = (const float*)d_in[1];
  const float* env    = (const float*)d_in[2];
  const float* dusk   = (const float*)d_in[3];
  const float* dawn   = (const float*)d_in[4];
  const float* Win    = (const float*)d_in[5];
  const float* bin    = (const float*)d_in[6];
  const float* Wih    = (const float*)d_in[7];
  const float* Whh    = (const float*)d_in[8];
  const float* bih    = (const float*)d_in[9];
  const float* bhh    = (const float*)d_in[10];
  const float* Wout   = (const float*)d_in[11];
  const float* bout   = (const float*)d_in[12];
  float* out = (float*)d_out;

  // ---- f32 scratch layout
  float* ws  = (float*)d_ws;
  float* S   = ws;                          // 30720*64
  float* P   = S + (size_t)KSTAT * TT;      // 8*2048*64
  float* U   = P + (size_t)KPART * NN * TT; // 131072
  float* lin = U + (size_t)NN * TT;
  float* h0b = lin + NN;
  float* h1b = h0b + 2 * NN;
  float* c0  = h1b + 2 * NN;
  float* c1  = c0 + NN;
  float* xs  = c1 + NN;
  uint32* sync = (uint32*)(xs + NN);        // 64 words (cnt, gen, pad)
  char*  f32_end = (char*)(sync + 64);
  const size_t f32_bytes = (size_t)(f32_end - (char*)d_ws);

  // ---- packed 12-bit W_ih/W_hh (both layers) + fp16 W_tail/W_out
  const size_t rows_per_w   = (size_t)2 * 4 * NN;
  const size_t packed_bytes = rows_per_w * 64 * 48;
  const size_t n_tail = (size_t)NN * NN;
  const size_t n_out  = (size_t)NN * NN;

  uint4*     PIH  = (uint4*)((char*)d_ws + f32_bytes);
  uint4*     PHH  = (uint4*)((char*)PIH + packed_bytes);
  _Float16*  Wt16 = (_Float16*)((char*)PHH + packed_bytes);
  _Float16*  Wo16 = Wt16 + n_tail;
  const size_t needed = f32_bytes + 2 * packed_bytes + (n_tail + n_out) * sizeof(_Float16);
  const bool use_q = (ws_size >= needed);

  if (use_q){
    k_pack<<<dim3((int)(rows_per_w / 4)), dim3(256), 0, stream>>>(Wih, PIH);
    k_pack<<<dim3((int)(rows_per_w / 4)), dim3(256), 0, stream>>>(Whh, PHH);
    k_cvt_tail<<<dim3(NN), dim3(256), 0, stream>>>(Win, Wt16);
    k_cvt<<<dim3((int)(n_out / 8 / 256)), dim3(256), 0, stream>>>(Wout, Wo16);
  }

  k_gather<<<dim3((KSTAT * TT) / 256), dim3(256), 0, stream>>>(coords, env, dusk, dawn, S);
  k_pre<<<dim3(128, KPART), dim3(256), 0, stream>>>(Win, S, P);
  k_reduce<<<dim3(NN * TT / 256), dim3(256), 0, stream>>>(P, bin, U);
  k_init<<<dim3(8), dim3(256), 0, stream>>>(x, xs, h0b, h1b, c0, c1, out, sync);

  if (use_q){
    k_run<<<dim3(RBLK), dim3(RTPB), 0, stream>>>(
        PIH, PHH, Wt16, Wo16, bih, bhh, bout, U,
        lin, h0b, h1b, c0, c1, xs, out, sync + 0, sync + 16);
  } else {
    const size_t LOFF = (size_t)4 * NN * NN;
    for (int t = 0; t < TT; ++t){
      const int p = t & 1;
      float* h0n = h0b + (1 - p) * NN;
      float* h0p = h0b + p * NN;
      float* h1n = h1b + (1 - p) * NN;
      float* h1p = h1b + p * NN;
      k_lin_t<float><<<dim3(NN / 4), dim3(256), 0, stream>>>(Win + KSTAT, (size_t)KIN, U, xs, lin, t);
      k_lstm_t<float><<<dim3(NN), dim3(256), 0, stream>>>(Wih, Whh, bih, bhh,
                                                          lin, h0p, c0, h0n);
      k_lstm_t<float><<<dim3(NN), dim3(256), 0, stream>>>(Wih + LOFF, Whh + LOFF,
                                                          bih + 4 * NN, bhh + 4 * NN,
                                                          h0n, h1p, c1, h1n);
      k_xout_t<float><<<dim3(NN / 4), dim3(256), 0, stream>>>(Wout, bout, h1n, xs, out, t);
    }
  }
}

// Round 7
// 16576.579 us; speedup vs baseline: 1.2697x; 1.2697x over previous
//
#include <hip/hip_runtime.h>
#include <math.h>

#define NN    2048      // nodes == hidden
#define TT    64        // horizon
#define KIN   32768     // N_IN * N_NODES
#define KSTAT 30720     // static (non-recurrent) part of W_in columns
#define KPART 8         // K-split for k_pre
#define KC    (KSTAT / KPART)   // 3840
#define RBLK  256       // persistent-kernel blocks (1/CU, 2048 waves)
#define RTPB  512

typedef _Float16 half8v __attribute__((ext_vector_type(8)));
typedef unsigned int uint32;

__device__ __forceinline__ float wred(float v){
  #pragma unroll
  for (int m = 32; m > 0; m >>= 1) v += __shfl_xor(v, m, 64);
  return v;
}
__device__ __forceinline__ float sigm(float x){ return 1.0f / (1.0f + expf(-x)); }

__device__ __forceinline__ void load8(const _Float16* __restrict__ p, float* o){
  half8v h = *(const half8v*)p;
  #pragma unroll
  for (int i = 0; i < 8; ++i) o[i] = (float)h[i];
}
__device__ __forceinline__ void load8(const float* __restrict__ p, float* o){
  float4 a = *(const float4*)p, b = *(const float4*)(p + 4);
  o[0]=a.x; o[1]=a.y; o[2]=a.z; o[3]=a.w; o[4]=b.x; o[5]=b.y; o[6]=b.z; o[7]=b.w;
}

// ---------- decentralized flag barrier: store own flag, poll all (no RMW) ----------
// flags[RBLK] contiguous u32 (8 cachelines). Phase is monotonic -> no ABA, no reset.
__device__ __forceinline__ void fbar(uint32* flags, uint32 ph, int bid){
  __syncthreads();
  if (threadIdx.x < 64){
    const int lane = threadIdx.x;
    if (lane == 0){
      __builtin_amdgcn_fence(__ATOMIC_RELEASE, "agent");
      __hip_atomic_store(flags + bid, ph, __ATOMIC_RELAXED, __HIP_MEMORY_SCOPE_AGENT);
    }
    bool ok = false;
    while (!ok){
      uint32 a = __hip_atomic_load(flags + lane,       __ATOMIC_RELAXED, __HIP_MEMORY_SCOPE_AGENT);
      uint32 b = __hip_atomic_load(flags + lane +  64, __ATOMIC_RELAXED, __HIP_MEMORY_SCOPE_AGENT);
      uint32 c = __hip_atomic_load(flags + lane + 128, __ATOMIC_RELAXED, __HIP_MEMORY_SCOPE_AGENT);
      uint32 d = __hip_atomic_load(flags + lane + 192, __ATOMIC_RELAXED, __HIP_MEMORY_SCOPE_AGENT);
      ok = __all((a >= ph) && (b >= ph) && (c >= ph) && (d >= ph));
      if (!ok) __builtin_amdgcn_s_sleep(1);
    }
    if (lane == 0) __builtin_amdgcn_fence(__ATOMIC_ACQUIRE, "agent");
  }
  __syncthreads();
}

// ---------- f32 -> fp16 conversions ----------
__global__ void k_cvt(const float* __restrict__ s, _Float16* __restrict__ d){
  size_t i = ((size_t)blockIdx.x * 256 + threadIdx.x) * 8;
  float v[8]; load8(s + i, v);
  half8v h;
  #pragma unroll
  for (int q = 0; q < 8; ++q) h[q] = (_Float16)v[q];
  *(half8v*)(d + i) = h;
}
__global__ void k_cvt_tail(const float* __restrict__ Win, _Float16* __restrict__ dst){
  int r = blockIdx.x, c = threadIdx.x * 8;
  float v[8]; load8(Win + (size_t)r * KIN + KSTAT + c, v);
  half8v h;
  #pragma unroll
  for (int q = 0; q < 8; ++q) h[q] = (_Float16)v[q];
  *(half8v*)(dst + (size_t)r * NN + c) = h;
}

// ---------- f32 -> packed 12-bit (1-5-6 truncated fp16) ----------
__global__ void k_pack(const float* __restrict__ W, uint4* __restrict__ P){
  const int row  = blockIdx.x * 4 + (threadIdx.x >> 6);
  const int lane = threadIdx.x & 63;
  const float4* W4 = (const float4*)(W + (size_t)row * NN);
  uint32 u[12] = {0,0,0,0,0,0,0,0,0,0,0,0};
  #pragma unroll
  for (int c = 0; c < 8; ++c){
    float4 v = W4[lane + (c << 6)];
    float vv[4] = {v.x, v.y, v.z, v.w};
    #pragma unroll
    for (int q = 0; q < 4; ++q){
      _Float16 h = (_Float16)vv[q];
      unsigned short us = __builtin_bit_cast(unsigned short, h);
      us = (unsigned short)((us + 8) & 0xFFF0);
      uint32 f = (uint32)(us >> 4);
      int k = 4 * c + q, bp = 12 * k, w = bp >> 5, off = bp & 31;
      u[w] |= f << off;
      if (off > 20) u[w + 1] |= f >> (32 - off);
    }
  }
  uint4* p = P + (size_t)row * 192 + lane;
  p[0]   = make_uint4(u[0], u[1], u[2],  u[3]);
  p[64]  = make_uint4(u[4], u[5], u[6],  u[7]);
  p[128] = make_uint4(u[8], u[9], u[10], u[11]);
}

// ---------- packed-weight dot: one wave, one row of 2048 ----------
__device__ __forceinline__ float dot_packed(const uint4* __restrict__ base, int row,
                                            const float4* __restrict__ v4, int lane){
  const uint4* p = base + (size_t)row * 192 + lane;
  uint4 A = p[0], B = p[64], C = p[128];
  uint32 u[12] = {A.x,A.y,A.z,A.w, B.x,B.y,B.z,B.w, C.x,C.y,C.z,C.w};
  float acc = 0.f;
  #pragma unroll
  for (int c = 0; c < 8; ++c){
    float4 v = v4[lane + (c << 6)];
    float vv[4] = {v.x, v.y, v.z, v.w};
    #pragma unroll
    for (int q = 0; q < 4; ++q){
      int k = 4 * c + q, bp = 12 * k, w = bp >> 5, off = bp & 31;
      uint32 f = u[w] >> off;
      if (off > 20) f |= u[w + 1] << (32 - off);
      f &= 0xFFFu;
      float wt = (float)__builtin_bit_cast(_Float16, (unsigned short)(f << 4));
      acc = fmaf(wt, vv[q], acc);
    }
  }
  return acc;
}

// ---------- LSTM unit: all 4 gates in one wave (cell update wave-local) ----------
__device__ __forceinline__ void lstm_unit(const uint4* __restrict__ Pih, const uint4* __restrict__ Phh,
    const float* __restrict__ bih_l, const float* __restrict__ bhh_l,
    const float* __restrict__ vin, const float* __restrict__ hprev,
    float* __restrict__ c, float* __restrict__ hout, int j, int lane)
{
  float g[4];
  #pragma unroll
  for (int gg = 0; gg < 4; ++gg){
    float a = dot_packed(Pih, gg * NN + j, (const float4*)vin,  lane)
            + dot_packed(Phh, gg * NN + j, (const float4*)hprev, lane);
    g[gg] = wred(a);
  }
  if (lane == 0){
    float gi = sigm(g[0] + bih_l[0 * NN + j] + bhh_l[0 * NN + j]);
    float gf = sigm(g[1] + bih_l[1 * NN + j] + bhh_l[1 * NN + j]);
    float gt = tanhf(g[2] + bih_l[2 * NN + j] + bhh_l[2 * NN + j]);
    float go = sigm(g[3] + bih_l[3 * NN + j] + bhh_l[3 * NN + j]);
    float cn = fmaf(gf, c[j], gi * gt);
    c[j] = cn;
    hout[j] = go * tanhf(cn);
  }
}

// ---------- persistent recurrent kernel: 2048 waves, flag barriers ----------
__global__ __launch_bounds__(RTPB, 4) void k_run(
  const uint4* __restrict__ PIH, const uint4* __restrict__ PHH,
  const _Float16* __restrict__ Wt16, const _Float16* __restrict__ Wo16,
  const float* __restrict__ bih, const float* __restrict__ bhh,
  const float* __restrict__ bout, const float* __restrict__ U,
  float* __restrict__ lin, float* __restrict__ h0b, float* __restrict__ h1b,
  float* __restrict__ c0, float* __restrict__ c1,
  float* __restrict__ xs, float* __restrict__ out,
  uint32* __restrict__ flags)
{
  const int bid  = (int)blockIdx.x;
  const int w    = bid * (RTPB / 64) + ((int)threadIdx.x >> 6);  // 0..2047
  const int lane = (int)threadIdx.x & 63;
  const size_t LROWS = (size_t)4 * NN * 192;
  uint32 ph = 0;

  for (int t = 0; t < TT; ++t){
    const int p = t & 1;
    const float* h0p = h0b + p * NN;  float* h0n = h0b + (1 - p) * NN;
    const float* h1p = h1b + p * NN;  float* h1n = h1b + (1 - p) * NN;

    // stage A: lin[w] = U[w][t] + Wt16[w,:] @ xs
    {
      const _Float16* wp = Wt16 + (size_t)w * NN + lane * 8;
      const float* xv = xs + lane * 8;
      float acc = 0.f;
      #pragma unroll
      for (int ch = 0; ch < 4; ++ch){
        float wf[8], vf[8];
        load8(wp + ch * 512, wf); load8(xv + ch * 512, vf);
        #pragma unroll
        for (int q = 0; q < 8; ++q) acc = fmaf(wf[q], vf[q], acc);
      }
      acc = wred(acc);
      if (lane == 0) lin[w] = U[(size_t)w * TT + t] + acc;
    }
    ph++; fbar(flags, ph, bid);

    // stage B: layer 0, unit w
    lstm_unit(PIH, PHH, bih, bhh, lin, h0p, c0, h0n, w, lane);
    ph++; fbar(flags, ph, bid);

    // stage C: layer 1, unit w
    lstm_unit(PIH + LROWS, PHH + LROWS, bih + 4 * NN, bhh + 4 * NN,
              h0n, h1p, c1, h1n, w, lane);
    ph++; fbar(flags, ph, bid);

    // stage D: xs[w] += tanh(Wo16[w,:] @ h1n + bout[w])
    {
      const _Float16* wp = Wo16 + (size_t)w * NN + lane * 8;
      const float* hv = h1n + lane * 8;
      float acc = 0.f;
      #pragma unroll
      for (int ch = 0; ch < 4; ++ch){
        float wf[8], vf[8];
        load8(wp + ch * 512, wf); load8(hv + ch * 512, vf);
        #pragma unroll
        for (int q = 0; q < 8; ++q) acc = fmaf(wf[q], vf[q], acc);
      }
      acc = wred(acc);
      if (lane == 0){
        float xn = xs[w] + tanhf(acc + bout[w]);
        xs[w] = xn;
        out[(size_t)w * (TT + 1) + t + 1] = xn;
      }
    }
    ph++; fbar(flags, ph, bid);
  }
}

// ---------- gather static input matrix S[k][t] ----------
__global__ void k_gather(const float* __restrict__ coords, const float* __restrict__ env,
                         const float* __restrict__ dusk, const float* __restrict__ dawn,
                         float* __restrict__ S)
{
  int idx = blockIdx.x * 256 + threadIdx.x;
  int k = idx >> 6, t = idx & 63;
  float v;
  if (k < 4096)        v = coords[k];
  else if (k < 26624)  v = env[(size_t)(k - 4096) * 65 + t + 1];
  else if (k < 28672)  v = dusk[(size_t)(k - 26624) * 64 + t];
  else                 v = dawn[(size_t)(k - 28672) * 65 + t + 1];
  S[idx] = v;
}

// ---------- tiled GEMM: P[part][r][t] = sum_{k in part} W_in[r][k] * S[k][t] ----------
__global__ void k_pre(const float* __restrict__ Win, const float* __restrict__ S,
                      float* __restrict__ P)
{
  __shared__ float Wt[16 * 68];
  __shared__ float St[64 * 68];
  const int tid = threadIdx.x;
  const int rb  = blockIdx.x * 16;
  const int kp  = blockIdx.y;
  const int rc  = tid >> 4;
  const int t4  = (tid & 15) * 4;
  float4 acc = make_float4(0.f, 0.f, 0.f, 0.f);

  for (int kt = 0; kt < KC; kt += 64){
    const int kb = kp * KC + kt;
    __syncthreads();
    *(float4*)(Wt + rc * 68 + t4) =
        *(const float4*)(Win + (size_t)(rb + rc) * KIN + kb + t4);
    #pragma unroll
    for (int jj = 0; jj < 4; ++jj){
      int li = jj * 1024 + tid * 4;
      int kr = li >> 6, tc = li & 63;
      *(float4*)(St + kr * 68 + tc) =
          *(const float4*)(S + (size_t)(kb + kr) * 64 + tc);
    }
    __syncthreads();
    #pragma unroll
    for (int k = 0; k < 64; ++k){
      float w = Wt[rc * 68 + k];
      float4 s = *(const float4*)(St + k * 68 + t4);
      acc.x = fmaf(w, s.x, acc.x);
      acc.y = fmaf(w, s.y, acc.y);
      acc.z = fmaf(w, s.z, acc.z);
      acc.w = fmaf(w, s.w, acc.w);
    }
  }
  *(float4*)(P + ((size_t)kp * NN + rb + rc) * TT + t4) = acc;
}

// ---------- U[r][t] = b_in[r] + sum_p P[p][r][t] ----------
__global__ void k_reduce(const float* __restrict__ P, const float* __restrict__ bin,
                         float* __restrict__ U)
{
  int i = blockIdx.x * 256 + threadIdx.x;
  float s = bin[i >> 6];
  #pragma unroll
  for (int p = 0; p < KPART; ++p) s += P[(size_t)p * NN * TT + i];
  U[i] = s;
}

// ---------- init states + flags + output column 0 ----------
__global__ void k_init(const float* __restrict__ x, float* __restrict__ xs,
                       float* __restrict__ h0b, float* __restrict__ h1b,
                       float* __restrict__ c0, float* __restrict__ c1,
                       float* __restrict__ out, uint32* __restrict__ flags)
{
  int i = blockIdx.x * blockDim.x + threadIdx.x;
  if (i < RBLK) flags[i] = 0u;
  if (i < NN){
    float x0 = x[(size_t)i * (TT + 1)];
    xs[i] = x0;
    out[(size_t)i * (TT + 1)] = x0;
    h0b[i] = 0.f; h0b[NN + i] = 0.f;
    h1b[i] = 0.f; h1b[NN + i] = 0.f;
    c0[i] = 0.f;  c1[i] = 0.f;
  }
}

// ---------- f32 fallback kernels (used only if ws too small) ----------
template<typename WT>
__global__ void k_lin_t(const WT* __restrict__ Wtail, size_t wstride,
                        const float* __restrict__ U, const float* __restrict__ xs,
                        float* __restrict__ lin, int t)
{
  const int j    = blockIdx.x * 4 + (threadIdx.x >> 6);
  const int lane = threadIdx.x & 63;
  const WT* w = Wtail + (size_t)j * wstride + lane * 8;
  const float* xv = xs + lane * 8;
  float acc = 0.f;
  #pragma unroll
  for (int ch = 0; ch < 4; ++ch){
    float wf[8], vf[8];
    load8(w + ch * 512, wf);
    load8(xv + ch * 512, vf);
    #pragma unroll
    for (int q = 0; q < 8; ++q) acc = fmaf(wf[q], vf[q], acc);
  }
  acc = wred(acc);
  if (lane == 0) lin[j] = U[(size_t)j * TT + t] + acc;
}

template<typename WT>
__global__ void k_lstm_t(const WT* __restrict__ Wih_l, const WT* __restrict__ Whh_l,
                         const float* __restrict__ bih_l, const float* __restrict__ bhh_l,
                         const float* __restrict__ vin, const float* __restrict__ hprev,
                         float* __restrict__ c, float* __restrict__ hout)
{
  __shared__ float gsm[4];
  const int j    = blockIdx.x;
  const int g    = threadIdx.x >> 6;
  const int lane = threadIdx.x & 63;
  const WT* wi = Wih_l + (size_t)(g * NN + j) * NN + lane * 8;
  const WT* wh = Whh_l + (size_t)(g * NN + j) * NN + lane * 8;
  const float* vi = vin + lane * 8;
  const float* hp = hprev + lane * 8;
  float acc = 0.f;
  #pragma unroll
  for (int ch = 0; ch < 4; ++ch){
    float w1[8], w2[8], v1[8], v2[8];
    load8(wi + ch * 512, w1); load8(vi + ch * 512, v1);
    load8(wh + ch * 512, w2); load8(hp + ch * 512, v2);
    #pragma unroll
    for (int q = 0; q < 8; ++q) acc = fmaf(w1[q], v1[q], fmaf(w2[q], v2[q], acc));
  }
  acc = wred(acc);
  if (lane == 0) gsm[g] = acc + bih_l[g * NN + j] + bhh_l[g * NN + j];
  __syncthreads();
  if (threadIdx.x == 0){
    float gi = sigm(gsm[0]);
    float gf = sigm(gsm[1]);
    float gg = tanhf(gsm[2]);
    float go = sigm(gsm[3]);
    float cn = fmaf(gf, c[j], gi * gg);
    c[j] = cn;
    hout[j] = go * tanhf(cn);
  }
}

template<typename WT>
__global__ void k_xout_t(const WT* __restrict__ Wout, const float* __restrict__ bout,
                         const float* __restrict__ h1, float* __restrict__ xs,
                         float* __restrict__ out, int t)
{
  const int j    = blockIdx.x * 4 + (threadIdx.x >> 6);
  const int lane = threadIdx.x & 63;
  const WT* w = Wout + (size_t)j * NN + lane * 8;
  const float* hv = h1 + lane * 8;
  float acc = 0.f;
  #pragma unroll
  for (int ch = 0; ch < 4; ++ch){
    float wf[8], vf[8];
    load8(w + ch * 512, wf);
    load8(hv + ch * 512, vf);
    #pragma unroll
    for (int q = 0; q < 8; ++q) acc = fmaf(wf[q], vf[q], acc);
  }
  acc = wred(acc);
  if (lane == 0){
    float xn = xs[j] + tanhf(acc + bout[j]);
    xs[j] = xn;
    out[(size_t)j * (TT + 1) + t + 1] = xn;
  }
}

extern "C" void kernel_launch(void* const* d_in, const int* in_sizes, int n_in,
                              void* d_out, int out_size, void* d_ws, size_t ws_size,
                              hipStream_t stream)
{
  const float* x      = (const float*)d_in[0];
  const float* coords = (const float*)d_in[1];
  const float* env    = (const float*)d_in[2];
  const float* dusk   = (const float*)d_in[3];
  const float* dawn   = (const float*)d_in[4];
  const float* Win    = (const float*)d_in[5];
  const float* bin    = (const float*)d_in[6];
  const float* Wih    = (const float*)d_in[7];
  const float* Whh    = (const float*)d_in[8];
  const float* bih    = (const float*)d_in[9];
  const float* bhh    = (const float*)d_in[10];
  const float* Wout   = (const float*)d_in[11];
  const float* bout   = (const float*)d_in[12];
  float* out = (float*)d_out;

  // ---- f32 scratch layout
  float* ws  = (float*)d_ws;
  float* S   = ws;                          // 30720*64
  float* P   = S + (size_t)KSTAT * TT;      // 8*2048*64
  float* U   = P + (size_t)KPART * NN * TT; // 131072
  float* lin = U + (size_t)NN * TT;
  float* h0b = lin + NN;
  float* h1b = h0b + 2 * NN;
  float* c0  = h1b + 2 * NN;
  float* c1  = c0 + NN;
  float* xs  = c1 + NN;
  uint32* flags = (uint32*)(xs + NN);       // RBLK words
  char*  f32_end = (char*)(flags + RBLK);
  const size_t f32_bytes = (size_t)(f32_end - (char*)d_ws);

  // ---- packed 12-bit W_ih/W_hh (both layers) + fp16 W_tail/W_out
  const size_t rows_per_w   = (size_t)2 * 4 * NN;
  const size_t packed_bytes = rows_per_w * 64 * 48;
  const size_t n_tail = (size_t)NN * NN;
  const size_t n_out  = (size_t)NN * NN;

  uint4*     PIH  = (uint4*)((char*)d_ws + f32_bytes);
  uint4*     PHH  = (uint4*)((char*)PIH + packed_bytes);
  _Float16*  Wt16 = (_Float16*)((char*)PHH + packed_bytes);
  _Float16*  Wo16 = Wt16 + n_tail;
  const size_t needed = f32_bytes + 2 * packed_bytes + (n_tail + n_out) * sizeof(_Float16);
  const bool use_q = (ws_size >= needed);

  if (use_q){
    k_pack<<<dim3((int)(rows_per_w / 4)), dim3(256), 0, stream>>>(Wih, PIH);
    k_pack<<<dim3((int)(rows_per_w / 4)), dim3(256), 0, stream>>>(Whh, PHH);
    k_cvt_tail<<<dim3(NN), dim3(256), 0, stream>>>(Win, Wt16);
    k_cvt<<<dim3((int)(n_out / 8 / 256)), dim3(256), 0, stream>>>(Wout, Wo16);
  }

  k_gather<<<dim3((KSTAT * TT) / 256), dim3(256), 0, stream>>>(coords, env, dusk, dawn, S);
  k_pre<<<dim3(128, KPART), dim3(256), 0, stream>>>(Win, S, P);
  k_reduce<<<dim3(NN * TT / 256), dim3(256), 0, stream>>>(P, bin, U);
  k_init<<<dim3(8), dim3(256), 0, stream>>>(x, xs, h0b, h1b, c0, c1, out, flags);

  if (use_q){
    k_run<<<dim3(RBLK), dim3(RTPB), 0, stream>>>(
        PIH, PHH, Wt16, Wo16, bih, bhh, bout, U,
        lin, h0b, h1b, c0, c1, xs, out, flags);
  } else {
    const size_t LOFF = (size_t)4 * NN * NN;
    for (int t = 0; t < TT; ++t){
      const int p = t & 1;
      float* h0n = h0b + (1 - p) * NN;
      float* h0p = h0b + p * NN;
      float* h1n = h1b + (1 - p) * NN;
      float* h1p = h1b + p * NN;
      k_lin_t<float><<<dim3(NN / 4), dim3(256), 0, stream>>>(Win + KSTAT, (size_t)KIN, U, xs, lin, t);
      k_lstm_t<float><<<dim3(NN), dim3(256), 0, stream>>>(Wih, Whh, bih, bhh,
                                                          lin, h0p, c0, h0n);
      k_lstm_t<float><<<dim3(NN), dim3(256), 0, stream>>>(Wih + LOFF, Whh + LOFF,
                                                          bih + 4 * NN, bhh + 4 * NN,
                                                          h0n, h1p, c1, h1n);
      k_xout_t<float><<<dim3(NN / 4), dim3(256), 0, stream>>>(Wout, bout, h1n, xs, out, t);
    }
  }
}

// Round 8
// 1914.078 us; speedup vs baseline: 10.9958x; 8.6603x over previous
//
#include <hip/hip_runtime.h>
#include <math.h>

#define NN    2048      // nodes == hidden
#define TT    64        // horizon
#define KIN   32768     // N_IN * N_NODES
#define KSTAT 30720     // static (non-recurrent) part of W_in columns
#define KPART 8         // K-split for k_pre
#define KC    (KSTAT / KPART)   // 3840
#define RWORDS 640      // dwords per packed int10 row (64 lanes * 10)

typedef unsigned int uint32;

__device__ __forceinline__ float wred(float v){
  #pragma unroll
  for (int m = 32; m > 0; m >>= 1) v += __shfl_xor(v, m, 64);
  return v;
}
__device__ __forceinline__ float wredmax(float v){
  #pragma unroll
  for (int m = 32; m > 0; m >>= 1) v = fmaxf(v, __shfl_xor(v, m, 64));
  return v;
}
__device__ __forceinline__ float sigm(float x){ return 1.0f / (1.0f + expf(-x)); }

__device__ __forceinline__ void load8f(const float* __restrict__ p, float* o){
  float4 a = *(const float4*)p, b = *(const float4*)(p + 4);
  o[0]=a.x; o[1]=a.y; o[2]=a.z; o[3]=a.w; o[4]=b.x; o[5]=b.y; o[6]=b.z; o[7]=b.w;
}

// ---------- f32 -> packed int10, per-row scale ----------
// Lane owns weights {4*(lane+64c)+q : c=0..7,q=0..3}; field order k=4c+q.
// Row storage: plane0 uint4 (u0..u3), plane1 uint4 (u4..u7), plane2 uint2 (u8,u9).
__global__ void k_pack10(const float* __restrict__ W, size_t row_stride, int col_off,
                         uint32* __restrict__ P, float* __restrict__ scales)
{
  const int row  = blockIdx.x * 4 + (threadIdx.x >> 6);
  const int lane = threadIdx.x & 63;
  const float* wr = W + (size_t)row * row_stride + col_off;
  float w[32];
  float m = 0.f;
  #pragma unroll
  for (int c = 0; c < 8; ++c){
    float4 v = *(const float4*)(wr + 4 * (lane + (c << 6)));
    w[4*c+0] = v.x; w[4*c+1] = v.y; w[4*c+2] = v.z; w[4*c+3] = v.w;
    m = fmaxf(m, fmaxf(fmaxf(fabsf(v.x), fabsf(v.y)), fmaxf(fabsf(v.z), fabsf(v.w))));
  }
  m = wredmax(m);
  const float inv = (m > 0.f) ? 511.f / m : 0.f;
  if (lane == 0) scales[row] = (m > 0.f) ? m / 511.f : 0.f;

  uint32 u[10] = {0,0,0,0,0,0,0,0,0,0};
  #pragma unroll
  for (int k = 0; k < 32; ++k){
    int q = (int)rintf(w[k] * inv) + 512;
    q = (q < 0) ? 0 : ((q > 1023) ? 1023 : q);
    uint32 f = (uint32)q;
    int bp = 10 * k, wd = bp >> 5, off = bp & 31;
    u[wd] |= f << off;
    if (off > 22) u[wd + 1] |= f >> (32 - off);
  }
  uint32* p = P + (size_t)row * RWORDS;
  *(uint4*)(p + lane * 4)        = make_uint4(u[0], u[1], u[2], u[3]);
  *(uint4*)(p + 256 + lane * 4)  = make_uint4(u[4], u[5], u[6], u[7]);
  *(uint2*)(p + 512 + lane * 2)  = make_uint2(u[8], u[9]);
}

// ---------- packed int10 dot: one wave, one row of 2048; returns UNSCALED sum ----------
__device__ __forceinline__ float dot10(const uint32* __restrict__ base, int row,
                                       const float4* __restrict__ v4, int lane){
  const uint32* p = base + (size_t)row * RWORDS;
  uint4 A = *(const uint4*)(p + lane * 4);
  uint4 B = *(const uint4*)(p + 256 + lane * 4);
  uint2 C = *(const uint2*)(p + 512 + lane * 2);
  uint32 u[10] = {A.x,A.y,A.z,A.w, B.x,B.y,B.z,B.w, C.x,C.y};
  float acc = 0.f;
  #pragma unroll
  for (int c = 0; c < 8; ++c){
    float4 v = v4[lane + (c << 6)];
    float vv[4] = {v.x, v.y, v.z, v.w};
    #pragma unroll
    for (int q = 0; q < 4; ++q){
      int k = 4 * c + q, bp = 10 * k, wd = bp >> 5, off = bp & 31;
      uint32 f = u[wd] >> off;
      if (off > 22) f |= u[wd + 1] << (32 - off);   // folds at compile time
      f &= 1023u;
      acc = fmaf((float)((int)f - 512), vv[q], acc);
    }
  }
  return acc;
}

// ---------- gather static input matrix S[k][t] ----------
__global__ void k_gather(const float* __restrict__ coords, const float* __restrict__ env,
                         const float* __restrict__ dusk, const float* __restrict__ dawn,
                         float* __restrict__ S)
{
  int idx = blockIdx.x * 256 + threadIdx.x;
  int k = idx >> 6, t = idx & 63;
  float v;
  if (k < 4096)        v = coords[k];
  else if (k < 26624)  v = env[(size_t)(k - 4096) * 65 + t + 1];
  else if (k < 28672)  v = dusk[(size_t)(k - 26624) * 64 + t];
  else                 v = dawn[(size_t)(k - 28672) * 65 + t + 1];
  S[idx] = v;
}

// ---------- tiled GEMM: P[part][r][t] = sum_{k in part} W_in[r][k] * S[k][t] ----------
__global__ void k_pre(const float* __restrict__ Win, const float* __restrict__ S,
                      float* __restrict__ P)
{
  __shared__ float Wt[16 * 68];
  __shared__ float St[64 * 68];
  const int tid = threadIdx.x;
  const int rb  = blockIdx.x * 16;
  const int kp  = blockIdx.y;
  const int rc  = tid >> 4;
  const int t4  = (tid & 15) * 4;
  float4 acc = make_float4(0.f, 0.f, 0.f, 0.f);

  for (int kt = 0; kt < KC; kt += 64){
    const int kb = kp * KC + kt;
    __syncthreads();
    *(float4*)(Wt + rc * 68 + t4) =
        *(const float4*)(Win + (size_t)(rb + rc) * KIN + kb + t4);
    #pragma unroll
    for (int jj = 0; jj < 4; ++jj){
      int li = jj * 1024 + tid * 4;
      int kr = li >> 6, tc = li & 63;
      *(float4*)(St + kr * 68 + tc) =
          *(const float4*)(S + (size_t)(kb + kr) * 64 + tc);
    }
    __syncthreads();
    #pragma unroll
    for (int k = 0; k < 64; ++k){
      float w = Wt[rc * 68 + k];
      float4 s = *(const float4*)(St + k * 68 + t4);
      acc.x = fmaf(w, s.x, acc.x);
      acc.y = fmaf(w, s.y, acc.y);
      acc.z = fmaf(w, s.z, acc.z);
      acc.w = fmaf(w, s.w, acc.w);
    }
  }
  *(float4*)(P + ((size_t)kp * NN + rb + rc) * TT + t4) = acc;
}

// ---------- U[r][t] = b_in[r] + sum_p P[p][r][t] ----------
__global__ void k_reduce(const float* __restrict__ P, const float* __restrict__ bin,
                         float* __restrict__ U)
{
  int i = blockIdx.x * 256 + threadIdx.x;
  float s = bin[i >> 6];
  #pragma unroll
  for (int p = 0; p < KPART; ++p) s += P[(size_t)p * NN * TT + i];
  U[i] = s;
}

// ---------- init states + output column 0 ----------
__global__ void k_init(const float* __restrict__ x, float* __restrict__ xs,
                       float* __restrict__ h0b, float* __restrict__ h1b,
                       float* __restrict__ c0, float* __restrict__ c1,
                       float* __restrict__ out)
{
  int i = blockIdx.x * blockDim.x + threadIdx.x;
  if (i < NN){
    float x0 = x[(size_t)i * (TT + 1)];
    xs[i] = x0;
    out[(size_t)i * (TT + 1)] = x0;
    h0b[i] = 0.f; h0b[NN + i] = 0.f;
    h1b[i] = 0.f; h1b[NN + i] = 0.f;
    c0[i] = 0.f;  c1[i] = 0.f;
  }
}

// ---------- stage A: lin[j] = U[j][t] + scale_t[j] * (PT[j,:] . xs) ----------
__global__ void k_lin10(const uint32* __restrict__ PT, const float* __restrict__ sc_t,
                        const float* __restrict__ U, const float* __restrict__ xs,
                        float* __restrict__ lin, int t)
{
  const int j    = blockIdx.x * 4 + (threadIdx.x >> 6);
  const int lane = threadIdx.x & 63;
  float acc = wred(dot10(PT, j, (const float4*)xs, lane));
  if (lane == 0) lin[j] = U[(size_t)j * TT + t] + sc_t[j] * acc;
}

// ---------- LSTM layer: block per unit j, wave g per gate ----------
__global__ void k_lstm10(const uint32* __restrict__ Pih, const uint32* __restrict__ Phh,
                         const float* __restrict__ sc_ih, const float* __restrict__ sc_hh,
                         const float* __restrict__ bih_l, const float* __restrict__ bhh_l,
                         const float* __restrict__ vin, const float* __restrict__ hprev,
                         float* __restrict__ c, float* __restrict__ hout)
{
  __shared__ float gsm[4];
  const int j    = blockIdx.x;
  const int g    = threadIdx.x >> 6;
  const int lane = threadIdx.x & 63;
  const int row  = g * NN + j;
  float a1 = dot10(Pih, row, (const float4*)vin,   lane);
  float a2 = dot10(Phh, row, (const float4*)hprev, lane);
  float acc = wred(sc_ih[row] * a1 + sc_hh[row] * a2);
  if (lane == 0) gsm[g] = acc + bih_l[g * NN + j] + bhh_l[g * NN + j];
  __syncthreads();
  if (threadIdx.x == 0){
    float gi = sigm(gsm[0]);
    float gf = sigm(gsm[1]);
    float gg = tanhf(gsm[2]);
    float go = sigm(gsm[3]);
    float cn = fmaf(gf, c[j], gi * gg);
    c[j] = cn;
    hout[j] = go * tanhf(cn);
  }
}

// ---------- stage D: x += tanh(scale_o[j]*(PO[j,:] . h1) + b_out) ----------
__global__ void k_xout10(const uint32* __restrict__ PO, const float* __restrict__ sc_o,
                         const float* __restrict__ bout, const float* __restrict__ h1,
                         float* __restrict__ xs, float* __restrict__ out, int t)
{
  const int j    = blockIdx.x * 4 + (threadIdx.x >> 6);
  const int lane = threadIdx.x & 63;
  float acc = wred(dot10(PO, j, (const float4*)h1, lane));
  if (lane == 0){
    float xn = xs[j] + tanhf(sc_o[j] * acc + bout[j]);
    xs[j] = xn;
    out[(size_t)j * (TT + 1) + t + 1] = xn;
  }
}

// ---------- f32 fallback kernels (used only if ws too small) ----------
template<typename WT>
__global__ void k_lin_t(const WT* __restrict__ Wtail, size_t wstride,
                        const float* __restrict__ U, const float* __restrict__ xs,
                        float* __restrict__ lin, int t)
{
  const int j    = blockIdx.x * 4 + (threadIdx.x >> 6);
  const int lane = threadIdx.x & 63;
  const WT* w = Wtail + (size_t)j * wstride + lane * 8;
  const float* xv = xs + lane * 8;
  float acc = 0.f;
  #pragma unroll
  for (int ch = 0; ch < 4; ++ch){
    float wf[8], vf[8];
    load8f(w + ch * 512, wf);
    load8f(xv + ch * 512, vf);
    #pragma unroll
    for (int q = 0; q < 8; ++q) acc = fmaf(wf[q], vf[q], acc);
  }
  acc = wred(acc);
  if (lane == 0) lin[j] = U[(size_t)j * TT + t] + acc;
}

template<typename WT>
__global__ void k_lstm_t(const WT* __restrict__ Wih_l, const WT* __restrict__ Whh_l,
                         const float* __restrict__ bih_l, const float* __restrict__ bhh_l,
                         const float* __restrict__ vin, const float* __restrict__ hprev,
                         float* __restrict__ c, float* __restrict__ hout)
{
  __shared__ float gsm[4];
  const int j    = blockIdx.x;
  const int g    = threadIdx.x >> 6;
  const int lane = threadIdx.x & 63;
  const WT* wi = Wih_l + (size_t)(g * NN + j) * NN + lane * 8;
  const WT* wh = Whh_l + (size_t)(g * NN + j) * NN + lane * 8;
  const float* vi = vin + lane * 8;
  const float* hp = hprev + lane * 8;
  float acc = 0.f;
  #pragma unroll
  for (int ch = 0; ch < 4; ++ch){
    float w1[8], w2[8], v1[8], v2[8];
    load8f(wi + ch * 512, w1); load8f(vi + ch * 512, v1);
    load8f(wh + ch * 512, w2); load8f(hp + ch * 512, v2);
    #pragma unroll
    for (int q = 0; q < 8; ++q) acc = fmaf(w1[q], v1[q], fmaf(w2[q], v2[q], acc));
  }
  acc = wred(acc);
  if (lane == 0) gsm[g] = acc + bih_l[g * NN + j] + bhh_l[g * NN + j];
  __syncthreads();
  if (threadIdx.x == 0){
    float gi = sigm(gsm[0]);
    float gf = sigm(gsm[1]);
    float gg = tanhf(gsm[2]);
    float go = sigm(gsm[3]);
    float cn = fmaf(gf, c[j], gi * gg);
    c[j] = cn;
    hout[j] = go * tanhf(cn);
  }
}

template<typename WT>
__global__ void k_xout_t(const WT* __restrict__ Wout, const float* __restrict__ bout,
                         const float* __restrict__ h1, float* __restrict__ xs,
                         float* __restrict__ out, int t)
{
  const int j    = blockIdx.x * 4 + (threadIdx.x >> 6);
  const int lane = threadIdx.x & 63;
  const WT* w = Wout + (size_t)j * NN + lane * 8;
  const float* hv = h1 + lane * 8;
  float acc = 0.f;
  #pragma unroll
  for (int ch = 0; ch < 4; ++ch){
    float wf[8], vf[8];
    load8f(w + ch * 512, wf);
    load8f(hv + ch * 512, vf);
    #pragma unroll
    for (int q = 0; q < 8; ++q) acc = fmaf(wf[q], vf[q], acc);
  }
  acc = wred(acc);
  if (lane == 0){
    float xn = xs[j] + tanhf(acc + bout[j]);
    xs[j] = xn;
    out[(size_t)j * (TT + 1) + t + 1] = xn;
  }
}

extern "C" void kernel_launch(void* const* d_in, const int* in_sizes, int n_in,
                              void* d_out, int out_size, void* d_ws, size_t ws_size,
                              hipStream_t stream)
{
  const float* x      = (const float*)d_in[0];
  const float* coords = (const float*)d_in[1];
  const float* env    = (const float*)d_in[2];
  const float* dusk   = (const float*)d_in[3];
  const float* dawn   = (const float*)d_in[4];
  const float* Win    = (const float*)d_in[5];
  const float* bin    = (const float*)d_in[6];
  const float* Wih    = (const float*)d_in[7];
  const float* Whh    = (const float*)d_in[8];
  const float* bih    = (const float*)d_in[9];
  const float* bhh    = (const float*)d_in[10];
  const float* Wout   = (const float*)d_in[11];
  const float* bout   = (const float*)d_in[12];
  float* out = (float*)d_out;

  // ---- f32 scratch layout
  float* ws  = (float*)d_ws;
  float* S   = ws;                          // 30720*64
  float* P   = S + (size_t)KSTAT * TT;      // 8*2048*64
  float* U   = P + (size_t)KPART * NN * TT; // 131072
  float* lin = U + (size_t)NN * TT;
  float* h0b = lin + NN;
  float* h1b = h0b + 2 * NN;
  float* c0  = h1b + 2 * NN;
  float* c1  = c0 + NN;
  float* xs  = c1 + NN;
  char*  f32_end = (char*)(xs + NN);
  const size_t f32_bytes = (size_t)(f32_end - (char*)d_ws);

  // ---- packed int10 weights + per-row scales
  const size_t rows_ihhh = (size_t)2 * 4 * NN;          // 16384 rows per matrix
  const size_t pw_ihhh   = rows_ihhh * RWORDS * 4;      // bytes: 41.9 MB each
  const size_t pw_small  = (size_t)NN * RWORDS * 4;     // 5.24 MB each

  uint32* PIH = (uint32*)((char*)d_ws + f32_bytes);
  uint32* PHH = (uint32*)((char*)PIH + pw_ihhh);
  uint32* PT  = (uint32*)((char*)PHH + pw_ihhh);
  uint32* PO  = (uint32*)((char*)PT + pw_small);
  float*  sc_ih = (float*)((char*)PO + pw_small);       // 16384
  float*  sc_hh = sc_ih + rows_ihhh;                    // 16384
  float*  sc_t  = sc_hh + rows_ihhh;                    // 2048
  float*  sc_o  = sc_t + NN;                            // 2048
  const size_t needed = f32_bytes + 2 * pw_ihhh + 2 * pw_small
                      + (2 * rows_ihhh + 2 * NN) * sizeof(float);
  const bool use_q = (ws_size >= needed);

  if (use_q){
    k_pack10<<<dim3((int)(rows_ihhh / 4)), dim3(256), 0, stream>>>(Wih, (size_t)NN, 0, PIH, sc_ih);
    k_pack10<<<dim3((int)(rows_ihhh / 4)), dim3(256), 0, stream>>>(Whh, (size_t)NN, 0, PHH, sc_hh);
    k_pack10<<<dim3(NN / 4), dim3(256), 0, stream>>>(Win, (size_t)KIN, KSTAT, PT, sc_t);
    k_pack10<<<dim3(NN / 4), dim3(256), 0, stream>>>(Wout, (size_t)NN, 0, PO, sc_o);
  }

  k_gather<<<dim3((KSTAT * TT) / 256), dim3(256), 0, stream>>>(coords, env, dusk, dawn, S);
  k_pre<<<dim3(128, KPART), dim3(256), 0, stream>>>(Win, S, P);
  k_reduce<<<dim3(NN * TT / 256), dim3(256), 0, stream>>>(P, bin, U);
  k_init<<<dim3(8), dim3(256), 0, stream>>>(x, xs, h0b, h1b, c0, c1, out);

  const size_t LROWS = (size_t)4 * NN;   // row offset for layer 1
  for (int t = 0; t < TT; ++t){
    const int p = t & 1;
    float* h0n = h0b + (1 - p) * NN;
    float* h0p = h0b + p * NN;
    float* h1n = h1b + (1 - p) * NN;
    float* h1p = h1b + p * NN;
    if (use_q){
      k_lin10<<<dim3(NN / 4), dim3(256), 0, stream>>>(PT, sc_t, U, xs, lin, t);
      k_lstm10<<<dim3(NN), dim3(256), 0, stream>>>(PIH, PHH, sc_ih, sc_hh,
                                                   bih, bhh, lin, h0p, c0, h0n);
      k_lstm10<<<dim3(NN), dim3(256), 0, stream>>>(PIH + LROWS * RWORDS, PHH + LROWS * RWORDS,
                                                   sc_ih + LROWS, sc_hh + LROWS,
                                                   bih + 4 * NN, bhh + 4 * NN,
                                                   h0n, h1p, c1, h1n);
      k_xout10<<<dim3(NN / 4), dim3(256), 0, stream>>>(PO, sc_o, bout, h1n, xs, out, t);
    } else {
      const size_t LOFF = (size_t)4 * NN * NN;
      k_lin_t<float><<<dim3(NN / 4), dim3(256), 0, stream>>>(Win + KSTAT, (size_t)KIN, U, xs, lin, t);
      k_lstm_t<float><<<dim3(NN), dim3(256), 0, stream>>>(Wih, Whh, bih, bhh,
                                                          lin, h0p, c0, h0n);
      k_lstm_t<float><<<dim3(NN), dim3(256), 0, stream>>>(Wih + LOFF, Whh + LOFF,
                                                          bih + 4 * NN, bhh + 4 * NN,
                                                          h0n, h1p, c1, h1n);
      k_xout_t<float><<<dim3(NN / 4), dim3(256), 0, stream>>>(Wout, bout, h1n, xs, out, t);
    }
  }
}